// Round 1
// baseline (902.471 us; speedup 1.0000x reference)
//
#include <hip/hip_runtime.h>

// Sinkhorn with ragged masks, factorized into scaling vectors:
//   A = s + EPS (inside block), R/C scaling vectors.
//   col update: C[j] = 1 / sum_{i<nr} A[i,j]*R[i]
//   row update: R[i] = 1 / sum_{j<nc} A[i,j]*C[j]
//   5 of each, interleaved starting with col (R=1). out = A*R*C in block, 0 outside.
// fp16 copy of A staged in (lower half of) d_out so the 9 re-read passes are
// L3-resident; first col pass fused into the compression (exact fp32).

#define BB 64
#define NN 1024
#define MM 1024
#define EPS 1e-4f

typedef _Float16 half_t;
typedef __attribute__((ext_vector_type(2))) _Float16 half2_t;
typedef __attribute__((ext_vector_type(8))) _Float16 half8_t;
typedef __attribute__((ext_vector_type(2))) float float2_t;
typedef __attribute__((ext_vector_type(4))) float float4_t;

// Pass 1: read fp32 s, write fp16 A=s+eps (rows < nr, 128-col stripes < nc),
// and compute first col sums (R=1) exactly in fp32.
// grid (MM/128, BB), block 256 = 64 col-pair lanes x 4 row groups.
__global__ __launch_bounds__(256) void prep_kernel(
    const float* __restrict__ s, const int* __restrict__ nrows,
    const int* __restrict__ ncols, half_t* __restrict__ H,
    float* __restrict__ C) {
  int b = blockIdx.y;
  int nr = nrows[b], nc = ncols[b];
  int c = threadIdx.x & 63;
  int rg = threadIdx.x >> 6;
  int j0 = blockIdx.x * 128 + c * 2;
  if (blockIdx.x * 128 >= nc) {  // stripe fully outside: C=0, no H needed
    if (rg == 0) { C[b * MM + j0] = 0.f; C[b * MM + j0 + 1] = 0.f; }
    return;
  }
  const float* sp = s + (size_t)b * NN * MM;
  half_t* hp = H + (size_t)b * NN * MM;
  float ax = 0.f, ay = 0.f;
  for (int i = rg; i < nr; i += 4) {
    float2_t v = *(const float2_t*)(sp + (size_t)i * MM + j0);
    float vx = v.x + EPS, vy = v.y + EPS;
    half2_t h;
    h.x = (half_t)vx; h.y = (half_t)vy;
    *(half2_t*)(hp + (size_t)i * MM + j0) = h;
    ax += vx; ay += vy;
  }
  __shared__ float part[4][64][2];
  part[rg][c][0] = ax; part[rg][c][1] = ay;
  __syncthreads();
  if (rg == 0) {
    for (int k = 1; k < 4; k++) { ax += part[k][c][0]; ay += part[k][c][1]; }
    C[b * MM + j0]     = (j0     < nc) ? 1.f / ax : 0.f;
    C[b * MM + j0 + 1] = (j0 + 1 < nc) ? 1.f / ay : 0.f;
  }
}

// col update: C[j] = 1/sum_{i<nr} H[i,j]*R[i].  grid (MM/128, BB), block 256.
__global__ __launch_bounds__(256) void col_kernel(
    const half_t* __restrict__ H, const int* __restrict__ nrows,
    const int* __restrict__ ncols, const float* __restrict__ R,
    float* __restrict__ C) {
  int b = blockIdx.y;
  int nr = nrows[b], nc = ncols[b];
  int c = threadIdx.x & 63;
  int rg = threadIdx.x >> 6;
  int j0 = blockIdx.x * 128 + c * 2;
  if (blockIdx.x * 128 >= nc) {
    if (rg == 0) { C[b * MM + j0] = 0.f; C[b * MM + j0 + 1] = 0.f; }
    return;
  }
  const half_t* hp = H + (size_t)b * NN * MM;
  const float* Rp = R + b * NN;
  float ax = 0.f, ay = 0.f;
  for (int i = rg; i < nr; i += 4) {
    half2_t h = *(const half2_t*)(hp + (size_t)i * MM + j0);
    float rv = Rp[i];
    ax += (float)h.x * rv;
    ay += (float)h.y * rv;
  }
  __shared__ float part[4][64][2];
  part[rg][c][0] = ax; part[rg][c][1] = ay;
  __syncthreads();
  if (rg == 0) {
    for (int k = 1; k < 4; k++) { ax += part[k][c][0]; ay += part[k][c][1]; }
    C[b * MM + j0]     = (j0     < nc) ? 1.f / ax : 0.f;
    C[b * MM + j0 + 1] = (j0 + 1 < nc) ? 1.f / ay : 0.f;
  }
}

// row update: R[i] = 1/sum_{j<nc} H[i,j]*C[j].  One wave per row.
// grid (NN/4, BB), block 256 = 4 waves. C[j>=nc]==0 masks the vector tail.
__global__ __launch_bounds__(256) void row_kernel(
    const half_t* __restrict__ H, const int* __restrict__ nrows,
    const int* __restrict__ ncols, const float* __restrict__ C,
    float* __restrict__ R) {
  int b = blockIdx.y;
  int nr = nrows[b], nc = ncols[b];
  int w = threadIdx.x >> 6;
  int l = threadIdx.x & 63;
  int i = blockIdx.x * 4 + w;
  if (i >= nr) {
    if (l == 0) R[b * NN + i] = 0.f;
    return;
  }
  const half_t* hp = H + ((size_t)b * NN + i) * MM;
  const float* Cp = C + b * MM;
  float acc = 0.f;
  for (int chunk = 0; chunk * 512 < nc; chunk++) {
    int base = chunk * 512 + l * 8;
    if (base < nc) {
      half8_t h = *(const half8_t*)(hp + base);
      float4_t c0 = *(const float4_t*)(Cp + base);
      float4_t c1 = *(const float4_t*)(Cp + base + 4);
      acc += (float)h[0] * c0.x + (float)h[1] * c0.y + (float)h[2] * c0.z +
             (float)h[3] * c0.w + (float)h[4] * c1.x + (float)h[5] * c1.y +
             (float)h[6] * c1.z + (float)h[7] * c1.w;
    }
  }
  for (int off = 32; off > 0; off >>= 1) acc += __shfl_xor(acc, off, 64);
  if (l == 0) R[b * NN + i] = 1.f / acc;
}

// out = (s+eps)*R[i]*C[j]; zeros outside block come free since R/C are 0 there,
// but we skip the s read entirely for fully-masked rows/quads.
// grid (NN, BB), block 256, float4 per thread.
__global__ __launch_bounds__(256) void final_kernel(
    const float* __restrict__ s, const int* __restrict__ nrows,
    const int* __restrict__ ncols, const float* __restrict__ R,
    const float* __restrict__ C, float* __restrict__ out) {
  int b = blockIdx.y;
  int i = blockIdx.x;
  int j = threadIdx.x * 4;
  size_t off = ((size_t)b * NN + i) * MM + j;
  int nr = nrows[b];
  if (i >= nr) {
    *(float4_t*)(out + off) = (float4_t){0.f, 0.f, 0.f, 0.f};
    return;
  }
  int nc = ncols[b];
  if (j >= nc) {
    *(float4_t*)(out + off) = (float4_t){0.f, 0.f, 0.f, 0.f};
    return;
  }
  float rv = R[b * NN + i];
  float4_t c4 = *(const float4_t*)(C + b * MM + j);
  float4_t s4 = *(const float4_t*)(s + off);
  float4_t o;
  o.x = (s4.x + EPS) * rv * c4.x;
  o.y = (s4.y + EPS) * rv * c4.y;
  o.z = (s4.z + EPS) * rv * c4.z;
  o.w = (s4.w + EPS) * rv * c4.w;
  *(float4_t*)(out + off) = o;
}

extern "C" void kernel_launch(void* const* d_in, const int* in_sizes, int n_in,
                              void* d_out, int out_size, void* d_ws,
                              size_t ws_size, hipStream_t stream) {
  const float* s = (const float*)d_in[0];
  const int* nrows = (const int*)d_in[1];
  const int* ncols = (const int*)d_in[2];
  float* out = (float*)d_out;
  // fp16 copy of A lives in the lower 128MB of d_out (final pass doesn't read it)
  half_t* H = (half_t*)d_out;
  // R (B*N) and C (B*M) scaling vectors in workspace (512KB)
  float* R = (float*)d_ws;
  float* C = R + BB * NN;

  dim3 cgrid(MM / 128, BB);
  dim3 rgrid(NN / 4, BB);

  // col pass 1 fused with fp16 compression (exact fp32 sums, R=1)
  prep_kernel<<<cgrid, 256, 0, stream>>>(s, nrows, ncols, H, C);
  // remaining: row,col,row,col,row,col,row,col,row  (5 row + 4 col)
  for (int t = 0; t < 5; t++) {
    row_kernel<<<rgrid, 256, 0, stream>>>(H, nrows, ncols, C, R);
    if (t < 4) col_kernel<<<cgrid, 256, 0, stream>>>(H, nrows, ncols, R, C);
  }
  final_kernel<<<dim3(NN, BB), 256, 0, stream>>>(s, nrows, ncols, R, C, out);
}

// Round 2
// 598.477 us; speedup vs baseline: 1.5079x; 1.5079x over previous
//
#include <hip/hip_runtime.h>

// Sinkhorn with ragged masks, factorized into scaling vectors:
//   A = s + EPS (inside block), R/C scaling vectors.
//   col update: C[j] = 1 / sum_{i<nr} A[i,j]*R[i]
//   row update: R[i] = 1 / sum_{j<nc} A[i,j]*C[j]
// 10 alternating updates starting with col (R=1): col is fused into prep
// (exact fp32), the last row update is fused with the output scale (exact
// fp32 from s). Middle 8 passes read a fp16 copy H of A (75MB in-block,
// L3-resident) staged in the lower half of d_out.
// Col-sum passes are split into 8 row-chunks (partials in ws) for occupancy.

#define BB 64
#define NN 1024
#define MM 1024
#define EPS 1e-4f

typedef _Float16 half_t;
typedef __attribute__((ext_vector_type(4))) _Float16 half4_t;
typedef __attribute__((ext_vector_type(8))) _Float16 half8_t;
typedef __attribute__((ext_vector_type(4))) float float4_t;

// prep: H=(half)(s+eps) + fp32 partial col sums (first col update, R=1).
// grid (8 stripes of 128 cols, 8 row-chunks of 128, BB), block 256.
__global__ __launch_bounds__(256) void prep_kernel(
    const float* __restrict__ s, const int* __restrict__ nrows,
    const int* __restrict__ ncols, half_t* __restrict__ H,
    float* __restrict__ P) {
  int b = blockIdx.z, rc = blockIdx.y, stripe = blockIdx.x;
  int nr = nrows[b], nc = ncols[b];
  float* Pp = P + ((size_t)rc * BB + b) * MM + stripe * 128;
  if (stripe * 128 >= nc) {  // stripe fully masked: zero partials
    if (threadIdx.x < 128) Pp[threadIdx.x] = 0.f;
    return;
  }
  int tc = threadIdx.x & 31, tr = threadIdx.x >> 5;
  int j0 = stripe * 128 + tc * 4;
  const float* sp = s + (size_t)b * NN * MM + j0;
  half_t* hp = H + (size_t)b * NN * MM + j0;
  float4_t acc = {0.f, 0.f, 0.f, 0.f};
  int base = rc * 128;
#pragma unroll
  for (int it = 0; it < 16; it++) {
    int i = base + it * 8 + tr;
    if (i < nr) {
      float4_t v = *(const float4_t*)(sp + (size_t)i * MM);
      v.x += EPS; v.y += EPS; v.z += EPS; v.w += EPS;
      half4_t h = {(half_t)v.x, (half_t)v.y, (half_t)v.z, (half_t)v.w};
      *(half4_t*)(hp + (size_t)i * MM) = h;
      acc.x += v.x; acc.y += v.y; acc.z += v.z; acc.w += v.w;
    }
  }
  __shared__ float lds[8][128];
  *(float4_t*)&lds[tr][tc * 4] = acc;
  __syncthreads();
  if (threadIdx.x < 128) {
    float s0 = 0.f;
#pragma unroll
    for (int k = 0; k < 8; k++) s0 += lds[k][threadIdx.x];
    Pp[threadIdx.x] = s0;
  }
}

// fold 8 partials -> C[j] = (j<nc) ? 1/sum : 0.  grid (4, BB), block 256.
__global__ __launch_bounds__(256) void creduce_kernel(
    const float* __restrict__ P, const int* __restrict__ ncols,
    float* __restrict__ C) {
  int b = blockIdx.y;
  int j = blockIdx.x * 256 + threadIdx.x;
  int nc = ncols[b];
  float s0 = 0.f;
#pragma unroll
  for (int k = 0; k < 8; k++) s0 += P[((size_t)k * BB + b) * MM + j];
  C[b * MM + j] = (j < nc) ? 1.f / s0 : 0.f;
}

// row update: R[i] = 1/sum_{j<nc} H[i,j]*C[j]. One wave per row.
// grid (NN/4, BB), block 256. C[j>=nc]==0 masks vector tails.
__global__ __launch_bounds__(256) void row_kernel(
    const half_t* __restrict__ H, const int* __restrict__ nrows,
    const int* __restrict__ ncols, const float* __restrict__ C,
    float* __restrict__ R) {
  int b = blockIdx.y;
  int nr = nrows[b], nc = ncols[b];
  int w = threadIdx.x >> 6, l = threadIdx.x & 63;
  int i = blockIdx.x * 4 + w;
  if (i >= nr) return;  // R[i>=nr] never read
  const half_t* hp = H + ((size_t)b * NN + i) * MM;
  const float* Cp = C + b * MM;
  float acc = 0.f;
#pragma unroll
  for (int ch = 0; ch < 2; ch++) {
    int base = ch * 512 + l * 8;
    if (base < nc) {
      half8_t h = *(const half8_t*)(hp + base);
      float4_t c0 = *(const float4_t*)(Cp + base);
      float4_t c1 = *(const float4_t*)(Cp + base + 4);
      acc += (float)h[0] * c0.x + (float)h[1] * c0.y + (float)h[2] * c0.z +
             (float)h[3] * c0.w + (float)h[4] * c1.x + (float)h[5] * c1.y +
             (float)h[6] * c1.z + (float)h[7] * c1.w;
    }
  }
#pragma unroll
  for (int off = 32; off > 0; off >>= 1) acc += __shfl_xor(acc, off, 64);
  if (l == 0) R[b * NN + i] = 1.f / acc;
}

// col update partials: P[rc][b][j] = sum_{i in chunk rc, i<nr} H[i,j]*R[i].
// grid (4 stripes of 256 cols, 8 row-chunks, BB), block 256.
__global__ __launch_bounds__(256) void col_kernel(
    const half_t* __restrict__ H, const int* __restrict__ nrows,
    const int* __restrict__ ncols, const float* __restrict__ R,
    float* __restrict__ P) {
  int b = blockIdx.z, rc = blockIdx.y, stripe = blockIdx.x;
  int nr = nrows[b], nc = ncols[b];
  float* Pp = P + ((size_t)rc * BB + b) * MM + stripe * 256;
  if (stripe * 256 >= nc) {
    Pp[threadIdx.x] = 0.f;
    return;
  }
  int tc = threadIdx.x & 31, tr = threadIdx.x >> 5;
  int j0 = stripe * 256 + tc * 8;
  const half_t* hp = H + (size_t)b * NN * MM + j0;
  const float* Rp = R + b * NN;
  float acc[8] = {0.f, 0.f, 0.f, 0.f, 0.f, 0.f, 0.f, 0.f};
  int base = rc * 128;
#pragma unroll
  for (int it = 0; it < 16; it++) {
    int i = base + it * 8 + tr;
    if (i < nr) {
      half8_t h = *(const half8_t*)(hp + (size_t)i * MM);
      float r = Rp[i];
#pragma unroll
      for (int k = 0; k < 8; k++) acc[k] += (float)h[k] * r;
    }
  }
  __shared__ float lds[8][256];
#pragma unroll
  for (int k = 0; k < 8; k++) lds[tr][tc * 8 + k] = acc[k];
  __syncthreads();
  float s0 = 0.f;
#pragma unroll
  for (int k = 0; k < 8; k++) s0 += lds[k][threadIdx.x];
  Pp[threadIdx.x] = s0;
}

// last row update fused with output: row sum from exact fp32 s (held in
// registers), then out = (s+eps)*C*(1/rowsum); zeros for i>=nr / j>=nc.
// One wave per row, grid (NN/4, BB), block 256.
__global__ __launch_bounds__(256) void final_kernel(
    const float* __restrict__ s, const int* __restrict__ nrows,
    const int* __restrict__ ncols, const float* __restrict__ C,
    float* __restrict__ out) {
  int b = blockIdx.y;
  int nr = nrows[b], nc = ncols[b];
  int w = threadIdx.x >> 6, l = threadIdx.x & 63;
  int i = blockIdx.x * 4 + w;
  float* op = out + ((size_t)b * NN + i) * MM;
  float4_t z = {0.f, 0.f, 0.f, 0.f};
  if (i >= nr) {
#pragma unroll
    for (int ch = 0; ch < 4; ch++) *(float4_t*)(op + ch * 256 + l * 4) = z;
    return;
  }
  const float* sp = s + ((size_t)b * NN + i) * MM;
  const float* Cp = C + b * MM;
  float4_t sv[4], cv[4];
  float acc = 0.f;
  int nch = (nc + 255) >> 8;
#pragma unroll
  for (int ch = 0; ch < 4; ch++) {
    if (ch < nch) {
      float4_t v = *(const float4_t*)(sp + ch * 256 + l * 4);
      v.x += EPS; v.y += EPS; v.z += EPS; v.w += EPS;
      sv[ch] = v;
      float4_t c = *(const float4_t*)(Cp + ch * 256 + l * 4);
      cv[ch] = c;
      acc += v.x * c.x + v.y * c.y + v.z * c.z + v.w * c.w;
    }
  }
#pragma unroll
  for (int off = 32; off > 0; off >>= 1) acc += __shfl_xor(acc, off, 64);
  float r = 1.f / acc;
#pragma unroll
  for (int ch = 0; ch < 4; ch++) {
    if (ch < nch) {
      float4_t o;
      o.x = sv[ch].x * cv[ch].x * r;
      o.y = sv[ch].y * cv[ch].y * r;
      o.z = sv[ch].z * cv[ch].z * r;
      o.w = sv[ch].w * cv[ch].w * r;
      *(float4_t*)(op + ch * 256 + l * 4) = o;
    } else {
      *(float4_t*)(op + ch * 256 + l * 4) = z;
    }
  }
}

extern "C" void kernel_launch(void* const* d_in, const int* in_sizes, int n_in,
                              void* d_out, int out_size, void* d_ws,
                              size_t ws_size, hipStream_t stream) {
  const float* s = (const float*)d_in[0];
  const int* nrows = (const int*)d_in[1];
  const int* ncols = (const int*)d_in[2];
  float* out = (float*)d_out;
  half_t* H = (half_t*)d_out;  // fp16 A in lower 128MB of d_out; final pass
                               // never reads H, so out-writes can't race it
  float* R = (float*)d_ws;                 // [BB*NN]
  float* C = R + BB * NN;                  // [BB*MM]
  float* P = C + BB * MM;                  // [8][BB][MM] partial col sums

  dim3 pgrid(8, 8, BB);    // 4096 blocks
  dim3 cgrid(4, 8, BB);    // 2048 blocks
  dim3 rgrid(NN / 4, BB);  // 16384 blocks
  dim3 dgrid(4, BB);

  prep_kernel<<<pgrid, 256, 0, stream>>>(s, nrows, ncols, H, P);
  creduce_kernel<<<dgrid, 256, 0, stream>>>(P, ncols, C);
  for (int t = 0; t < 4; t++) {
    row_kernel<<<rgrid, 256, 0, stream>>>(H, nrows, ncols, C, R);
    col_kernel<<<cgrid, 256, 0, stream>>>(H, nrows, ncols, R, P);
    creduce_kernel<<<dgrid, 256, 0, stream>>>(P, ncols, C);
  }
  final_kernel<<<rgrid, 256, 0, stream>>>(s, nrows, ncols, C, out);
}